// Round 9
// baseline (225.231 us; speedup 1.0000x reference)
//
#include <hip/hip_runtime.h>

typedef unsigned short u16;
typedef short short8 __attribute__((ext_vector_type(8)));
typedef float floatx4 __attribute__((ext_vector_type(4)));
typedef u16 u16x4 __attribute__((ext_vector_type(4)));
typedef u16 u16x8 __attribute__((ext_vector_type(8)));

#define DEVI __device__ __forceinline__

DEVI u16 f2bf(float x) {
    union { float f; unsigned u; } c; c.f = x;
    unsigned u = c.u;
    u += 0x7fffu + ((u >> 16) & 1u);   // RNE
    return (u16)(u >> 16);
}
DEVI float bf2f(u16 h) {
    union { unsigned u; float f; } c; c.u = ((unsigned)h) << 16;
    return c.f;
}

DEVI void gload_lds16(const void* g, void* l) {
    auto gp = (const __attribute__((address_space(1))) unsigned*)(unsigned long long)g;
    auto lp = (__attribute__((address_space(3))) unsigned*)(unsigned)(unsigned long long)l;
    __builtin_amdgcn_global_load_lds(gp, lp, 16, 0, 0);
}

// ---------------- prep: conversions [0,768) + GroupNorm [768,1280) + WvT [1280,1296) + d [1296,1298)
__global__ __launch_bounds__(256) void prep_kernel(const float* __restrict__ qkv_w, u16* __restrict__ wq,
                                                   const float* __restrict__ out_w, u16* __restrict__ wob,
                                                   u16* __restrict__ wvT,
                                                   const float* __restrict__ qkv_b, float* __restrict__ dv,
                                                   const float* __restrict__ x,
                                                   const float* __restrict__ gw,
                                                   const float* __restrict__ gb,
                                                   u16* __restrict__ h) {
    const int bid = blockIdx.x;
    const int t = threadIdx.x;
    __shared__ u16 tile[128][132];     // used by transpose blocks only
    if (bid < 768) {
        // q,k rows of qkv_w (131072 float4) + out_w (65536 float4)
        int i = bid * 256 + t;
        const float* src; u16* dst; int j;
        if (i < 131072) { src = qkv_w; dst = wq; j = i; }
        else            { src = out_w; dst = wob; j = i - 131072; }
        float4 v = *(const float4*)&src[j * 4];
        u16x4 p; p[0] = f2bf(v.x); p[1] = f2bf(v.y); p[2] = f2bf(v.z); p[3] = f2bf(v.w);
        *(u16x4*)&dst[j * 4] = p;
    } else if (bid < 1280) {
        // ---- GroupNorm: single global read, stats + apply in regs ----
        const int bg = bid - 768;            // b*32+g
        const int b = bg >> 5, g = bg & 31;
        const float* xg = x + (long long)bg * 16384;
        const int n0 = t * 4;

        float4 xv[16];
        float s = 0.f, s2 = 0.f;
        #pragma unroll
        for (int cc = 0; cc < 16; cc++) {
            xv[cc] = *(const float4*)&xg[cc * 1024 + n0];
            s  += xv[cc].x + xv[cc].y + xv[cc].z + xv[cc].w;
            s2 += xv[cc].x*xv[cc].x + xv[cc].y*xv[cc].y + xv[cc].z*xv[cc].z + xv[cc].w*xv[cc].w;
        }
        #pragma unroll
        for (int m = 1; m < 64; m <<= 1) { s += __shfl_xor(s, m, 64); s2 += __shfl_xor(s2, m, 64); }
        __shared__ float rs[4], rq[4];
        if ((t & 63) == 0) { rs[t >> 6] = s; rq[t >> 6] = s2; }
        __syncthreads();
        float mean = (rs[0] + rs[1] + rs[2] + rs[3]) * (1.f / 16384.f);
        float var  = (rq[0] + rq[1] + rq[2] + rq[3]) * (1.f / 16384.f) - mean * mean;
        float rstd = rsqrtf(var + 1e-5f);

        u16x8 o[4][2];
        #pragma unroll
        for (int cc = 0; cc < 16; cc++) {
            int c = g * 16 + cc;
            float sc = gw[c] * rstd;
            float sh = gb[c] - mean * sc;
            o[0][cc >> 3][cc & 7] = f2bf(xv[cc].x * sc + sh);
            o[1][cc >> 3][cc & 7] = f2bf(xv[cc].y * sc + sh);
            o[2][cc >> 3][cc & 7] = f2bf(xv[cc].z * sc + sh);
            o[3][cc >> 3][cc & 7] = f2bf(xv[cc].w * sc + sh);
        }
        u16* hb = h + ((long long)b * 1024 + n0) * 512 + g * 16;
        #pragma unroll
        for (int k = 0; k < 4; k++) {
            *(u16x8*)&hb[(long long)k * 512]     = o[k][0];
            *(u16x8*)&hb[(long long)k * 512 + 8] = o[k][1];
        }
    } else if (bid < 1296) {
        // ---- LDS-tiled transpose: wvT[c][v] = bf16(Wv[v][c]), Wv = qkv_w rows [1024,1536) ----
        const int tb = bid - 1280;
        const int vbase = (tb >> 2) * 128, cbase = (tb & 3) * 128;
        #pragma unroll
        for (int rnd = 0; rnd < 16; rnd++) {
            int row = rnd * 8 + (t >> 5);       // v-row within tile
            int c4  = (t & 31) * 4;             // c-col within tile
            float4 v = *(const float4*)&qkv_w[(long long)(1024 + vbase + row) * 512 + cbase + c4];
            tile[row][c4 + 0] = f2bf(v.x);
            tile[row][c4 + 1] = f2bf(v.y);
            tile[row][c4 + 2] = f2bf(v.z);
            tile[row][c4 + 3] = f2bf(v.w);
        }
        __syncthreads();
        #pragma unroll
        for (int rnd = 0; rnd < 8; rnd++) {
            int r  = rnd * 16 + (t >> 4);       // c-row of output within tile
            int ch = (t & 15) * 8;              // v chunk
            u16x8 o;
            #pragma unroll
            for (int e = 0; e < 8; e++) o[e] = tile[ch + e][r];
            *(u16x8*)&wvT[(long long)(cbase + r) * 512 + vbase + ch] = o;
        }
    } else {
        // ---- d[o] = out_w[o][:] . qkv_b[1024:1536] (fp32 exact) ----
        int o = (bid - 1296) * 256 + t;
        const float4* r = (const float4*)(out_w + (long long)o * 512);
        const float4* b = (const float4*)(qkv_b + 1024);
        float s = 0.f;
        #pragma unroll 4
        for (int c = 0; c < 128; c++) {
            float4 a = r[c], q = b[c];
            s += a.x*q.x + a.y*q.y + a.z*q.z + a.w*q.w;
        }
        dv[o] = s;
    }
}

// ---------------- TN GEMM, 128x128 tile, BK=64 ----------------
// MODE 1: bf16 out ([m][n]), + optional fp32 row-bias (pre-round); STATS: store
//         E = exp(acc*scale) + per-row partial sum(E) per key-block
// MODE 2: bf16 transposed out C0[n][m] + bias[m]
// MODE 3: fp32 out = acc*invl[n] + bias[m] + res. aux = psum; invl computed in-kernel.
// NX>0: 1D launch, decoded so batch z runs on XCD z&7.
// FOLDW (MODE 2 only): blocks with blockIdx.x >= 128 compute the 512x512x512 product
//         C2 = A2 @ B2^T (MODE-1-style epilogue, no bias/stats), hiding W' = Wo@Wv.
template <int MODE, int NX, int NY, bool STATS, int MINW = 3, bool FOLDW = false>
__global__ __launch_bounds__(256, MINW)
void gemm_bt_kernel(const u16* __restrict__ A, const u16* __restrict__ Bt,
                    void* __restrict__ C0,
                    const float* __restrict__ bias, const float* __restrict__ res,
                    float* __restrict__ aux,
                    const u16* __restrict__ A2, const u16* __restrict__ B2, u16* __restrict__ C2,
                    float scale, int lda, int ldb, int ldc,
                    long long sA, long long sB, long long sC, long long sR, int K) {
    int bx, by, bz;
    if (NX > 0) {
        const int lid  = blockIdx.x;
        const int xcd  = lid & 7;
        const int slot = lid >> 3;
        const int per  = NX * NY;
        const int j    = slot / per;
        const int w    = slot - j * per;
        bz = xcd + 8 * j;
        bx = w % NX;
        by = w / NX;
    } else {
        bx = blockIdx.x; by = blockIdx.y; bz = blockIdx.z;
    }
    bool isW = false;
    int ldA = lda, ldB = ldb, ldC = ldc;
    const u16* Ap = A;
    const u16* Bp = Bt;
    if (FOLDW && bx >= 128) {
        isW = true;
        const int tb = (bx - 128) * 8 + by;   // 0..15
        bx = tb & 3; by = tb >> 2;
        Ap = A2; Bp = B2;
        ldA = 512; ldB = 512; ldC = 512;
    }
    const int t    = threadIdx.x;
    const int lane = t & 63;
    const int wave = t >> 6;
    const int m0   = by * 128;
    const int n0   = bx * 128;
    Ap += (long long)bz * sA;
    Bp += (long long)bz * sB;

    __shared__ __align__(16) u16 smem[16384];   // 32 KB: A[2][128][32] | B[2][128][32]
    u16* As = smem;
    u16* Bs = smem + 8192;

    const int wm = wave >> 1, wn = wave & 1;
    const int quad = lane >> 4, lrow = lane & 15;

    floatx4 acc[4][4];
    #pragma unroll
    for (int i = 0; i < 4; i++)
        #pragma unroll
        for (int j = 0; j < 4; j++)
            #pragma unroll
            for (int r = 0; r < 4; r++) acc[i][j][r] = 0.f;

    const int rowA = t >> 2;
    const int kch  = (t & 3) * 8;
    const u16* Ag = Ap + (long long)(m0 + rowA) * ldA + kch;
    const u16* Bg = Bp + (long long)(n0 + rowA) * ldB + kch;
    u16* Al = &As[t * 8];
    u16* Bl = &Bs[t * 8];
    const long long a64 = (long long)64 * ldA;
    const long long b64 = (long long)64 * ldB;

    for (int k0 = 0; k0 < K; k0 += 64) {
        gload_lds16(Ag + k0,            Al);
        gload_lds16(Ag + k0 + a64,      Al + 2048);
        gload_lds16(Ag + k0 + 32,       Al + 4096);
        gload_lds16(Ag + k0 + 32 + a64, Al + 6144);
        gload_lds16(Bg + k0,            Bl);
        gload_lds16(Bg + k0 + b64,      Bl + 2048);
        gload_lds16(Bg + k0 + 32,       Bl + 4096);
        gload_lds16(Bg + k0 + 32 + b64, Bl + 6144);
        __syncthreads();
        #pragma unroll
        for (int kk = 0; kk < 2; kk++) {
            short8 af[4], bfr[4];
            #pragma unroll
            for (int i = 0; i < 4; i++)
                af[i] = *(const short8*)&As[kk*4096 + (wm*64 + i*16 + lrow)*32 + quad*8];
            #pragma unroll
            for (int j = 0; j < 4; j++)
                bfr[j] = *(const short8*)&Bs[kk*4096 + (wn*64 + j*16 + lrow)*32 + quad*8];
            #pragma unroll
            for (int i = 0; i < 4; i++)
                #pragma unroll
                for (int j = 0; j < 4; j++)
                    acc[i][j] = __builtin_amdgcn_mfma_f32_16x16x32_bf16(af[i], bfr[j], acc[i][j], 0, 0, 0);
        }
        __syncthreads();
    }
    // smem free from here

    const int ST = 136;  // u16 row stride (272 B = 17*16)

    if (MODE == 1 || isW) {
        u16* Cbase = isW ? C2 : (u16*)C0;
        #pragma unroll
        for (int p = 0; p < 4; p++) {
            if (p) __syncthreads();
            if (wm == (p >> 1)) {
                #pragma unroll
                for (int ii = 0; ii < 2; ii++) {
                    const int i = (p & 1) * 2 + ii;
                    const int row = ii * 16 + quad * 4;
                    #pragma unroll
                    for (int j = 0; j < 4; j++) {
                        const int cB = wn * 64 + j * 16 + lrow;
                        #pragma unroll
                        for (int r = 0; r < 4; r++) {
                            float v = acc[i][j][r] * scale;
                            if (STATS && !isW) v = __expf(v);          // store E = exp(S*scale)
                            else if (!isW && bias) v += bias[m0 + p * 32 + row + r];
                            smem[(row + r) * ST + cB] = f2bf(v);
                        }
                    }
                }
            }
            __syncthreads();
            const int rr = t >> 3, cc = (t & 7) * 16;
            u16x8 a0 = *(u16x8*)&smem[rr * ST + cc];
            u16x8 a1 = *(u16x8*)&smem[rr * ST + cc + 8];
            u16* Cp = Cbase + (long long)bz * sC + (long long)(m0 + p * 32 + rr) * ldC + n0 + cc;
            *(u16x8*)Cp = a0;
            *(u16x8*)(Cp + 8) = a1;
            if (STATS && !isW) {
                // partial sum of E over this block's 128 key-cols, per query row
                // (sums the SAME bf16 values used as the softmax numerator)
                float ls = 0.f;
                #pragma unroll
                for (int e = 0; e < 8; e++)
                    ls += bf2f(a0[e]) + bf2f(a1[e]);
                #pragma unroll
                for (int m2 = 1; m2 < 8; m2 <<= 1) ls += __shfl_xor(ls, m2, 8);
                if ((t & 7) == 0)
                    aux[((long long)(bz * 8 + bx)) * 1024 + m0 + p * 32 + rr] = ls;
            }
        }
    } else if (MODE == 2) {
        #pragma unroll
        for (int p = 0; p < 4; p++) {
            if (p) __syncthreads();
            if (wn == (p >> 1)) {
                #pragma unroll
                for (int jj = 0; jj < 2; jj++) {
                    const int j = (p & 1) * 2 + jj;
                    const int row = jj * 16 + lrow;
                    #pragma unroll
                    for (int i = 0; i < 4; i++) {
                        const int mmL = wm * 64 + i * 16 + quad * 4;
                        u16x4 pk;
                        #pragma unroll
                        for (int r = 0; r < 4; r++)
                            pk[r] = f2bf(acc[i][j][r] + bias[m0 + mmL + r]);
                        *(u16x4*)&smem[row * ST + mmL] = pk;
                    }
                }
            }
            __syncthreads();
            const int rr = t >> 3, cc = (t & 7) * 16;
            u16x8 a0 = *(u16x8*)&smem[rr * ST + cc];
            u16x8 a1 = *(u16x8*)&smem[rr * ST + cc + 8];
            u16* Cp = (u16*)C0 + (long long)(n0 + p * 32 + rr) * ldC + m0 + cc;
            *(u16x8*)Cp = a0;
            *(u16x8*)(Cp + 8) = a1;
        }
    } else {
        // MODE 3: fp32 out = acc*invl[col] + bias[row] + res ; invl from psum in-kernel
        __shared__ float sinv[128];
        if (t < 128) {
            const float* pz = aux + ((long long)bz * 8) * 1024 + n0 + t;
            float l = 0.f;
            #pragma unroll
            for (int kb = 0; kb < 8; kb++) l += pz[(long long)kb * 1024];
            sinv[t] = 1.f / l;
        }
        float* smf = (float*)smem;
        const int SF = 132;
        float* C = (float*)C0 + (long long)bz * sC;
        const float* rz = res + (long long)bz * sR;
        #pragma unroll
        for (int p = 0; p < 8; p++) {
            if (p) __syncthreads();
            if (wm == (p >> 2)) {
                const int i = p & 3;
                #pragma unroll
                for (int j = 0; j < 4; j++) {
                    const int cB = wn * 64 + j * 16 + lrow;
                    #pragma unroll
                    for (int r = 0; r < 4; r++)
                        smf[(quad * 4 + r) * SF + cB] = acc[i][j][r];
                }
            }
            __syncthreads();   // orders sinv writes (p=0) and smf writes before reads
            const int rr = t >> 4, cc = (t & 15) * 8;
            const float bsv = bias[m0 + p * 16 + rr];
            float4 il0 = *(const float4*)&sinv[cc];
            float4 il1 = *(const float4*)&sinv[cc + 4];
            const long long gro = (long long)(m0 + p * 16 + rr) * ldC + n0 + cc;
            float4 rv0 = *(const float4*)&rz[gro];
            float4 rv1 = *(const float4*)&rz[gro + 4];
            float4 ov0, ov1;
            ov0.x = smf[rr*SF + cc + 0] * il0.x + bsv + rv0.x;
            ov0.y = smf[rr*SF + cc + 1] * il0.y + bsv + rv0.y;
            ov0.z = smf[rr*SF + cc + 2] * il0.z + bsv + rv0.z;
            ov0.w = smf[rr*SF + cc + 3] * il0.w + bsv + rv0.w;
            ov1.x = smf[rr*SF + cc + 4] * il1.x + bsv + rv1.x;
            ov1.y = smf[rr*SF + cc + 5] * il1.y + bsv + rv1.y;
            ov1.z = smf[rr*SF + cc + 6] * il1.z + bsv + rv1.z;
            ov1.w = smf[rr*SF + cc + 7] * il1.w + bsv + rv1.w;
            *(float4*)&C[gro]     = ov0;
            *(float4*)&C[gro + 4] = ov1;
        }
    }
}

extern "C" void kernel_launch(void* const* d_in, const int* in_sizes, int n_in,
                              void* d_out, int out_size, void* d_ws, size_t ws_size,
                              hipStream_t stream) {
    (void)in_sizes; (void)n_in; (void)out_size; (void)ws_size;
    const float* x     = (const float*)d_in[0];
    const float* gn_w  = (const float*)d_in[1];
    const float* gn_b  = (const float*)d_in[2];
    const float* qkv_w = (const float*)d_in[3];
    const float* qkv_b = (const float*)d_in[4];
    const float* out_w = (const float*)d_in[5];
    const float* out_b = (const float*)d_in[6];
    float* out = (float*)d_out;

    char* ws = (char*)d_ws;
    u16*  h_t   = (u16*)ws;  ws += (size_t)16*1024*512*2;    // 16 MB h[b][n][c]
    u16*  qkv_t = (u16*)ws;  ws += (size_t)16*1024*1536*2;   // qk[b*n][ld 1536] (cols 0..1023 used)
    u16*  vprm  = (u16*)ws;  ws += (size_t)512*16384*2;      // 16 MB V' = W' h^T + d : [c_out][b*1024+n]
    u16*  E     = (u16*)ws;  ws += (size_t)16*1024*1024*2;   // 32 MB E[b][n][m] = exp(S*scale), bf16
    u16*  wq    = (u16*)ws;  ws += (size_t)1024*512*2;       // bf16 q,k rows of qkv_w
    u16*  wob   = (u16*)ws;  ws += (size_t)512*512*2;        // bf16 out_w
    u16*  wvT   = (u16*)ws;  ws += (size_t)512*512*2;        // bf16 Wv^T [c_in][v]
    u16*  wprm  = (u16*)ws;  ws += (size_t)512*512*2;        // bf16 W' = Wo@Wv
    float* dv   = (float*)ws; ws += (size_t)512*4;           // d = Wo@qkv_b_v (fp32)
    float* psum = (float*)ws; ws += (size_t)16*8*1024*4;     // partial sum(E) per key-block

    // conversions + GroupNorm + Wv transpose + d, one launch
    prep_kernel<<<1298, 256, 0, stream>>>(qkv_w, wq, out_w, wob, wvT, qkv_b, dv,
                                          x, gn_w, gn_b, h_t);

    // QK: M=1024, Nn=16384, K=512 -> qkv_t[bn][ld1536] + bias (v folded away);
    // 16 extra blocks (bx>=128) compute W' = Wo @ Wv concurrently.
    gemm_bt_kernel<2, 0, 0, false, 3, true><<<dim3(130, 8, 1), 256, 0, stream>>>(
        wq, h_t, qkv_t, qkv_b, nullptr, nullptr,
        wob, wvT, wprm, 1.0f,
        512, 512, 1536, 0, 0, 0, 0, 512);

    // V' = W' @ h^T + d : M=512(c_out), Nn=16384(bn), K=512(c_in)
    gemm_bt_kernel<1, 0, 0, false, 3><<<dim3(128, 4, 1), 256, 0, stream>>>(
        wprm, h_t, vprm, dv, nullptr, nullptr,
        nullptr, nullptr, nullptr, 1.0f,
        512, 512, 16384, 0, 0, 0, 0, 512);

    // E = exp(q k^T * scale) : per batch M=Nn=1024, K=512 ; XCD-affine + partial sum(E) stats
    // 1024 blocks = exactly 1 full round at 4 blocks/CU.
    gemm_bt_kernel<1, 8, 8, true, 4><<<1024, 256, 0, stream>>>(
        qkv_t, qkv_t + 512, E, nullptr, nullptr, psum,
        nullptr, nullptr, nullptr, 0.044194173824159216f,
        1536, 1536, 1024,
        (long long)1024*1536, (long long)1024*1536, (long long)1024*1024, 0, 512);

    // out = vprm ⊗ E * invl + out_b + x : M=512, Nn=1024(n), K=1024(m) ; XCD-affine,
    // plain DMA B, invl computed in-kernel from psum
    gemm_bt_kernel<3, 8, 4, false, 3><<<512, 256, 0, stream>>>(
        vprm, E, out, out_b, x, psum,
        nullptr, nullptr, nullptr, 1.0f,
        16384, 1024, 1024,
        1024, (long long)1024*1024, (long long)512*1024, (long long)512*1024, 1024);
}

// Round 10
// 199.261 us; speedup vs baseline: 1.1303x; 1.1303x over previous
//
#include <hip/hip_runtime.h>

typedef unsigned short u16;
typedef short short8 __attribute__((ext_vector_type(8)));
typedef float floatx4 __attribute__((ext_vector_type(4)));
typedef u16 u16x4 __attribute__((ext_vector_type(4)));
typedef u16 u16x8 __attribute__((ext_vector_type(8)));

#define DEVI __device__ __forceinline__

DEVI u16 f2bf(float x) {
    union { float f; unsigned u; } c; c.f = x;
    unsigned u = c.u;
    u += 0x7fffu + ((u >> 16) & 1u);   // RNE
    return (u16)(u >> 16);
}
DEVI float bf2f(u16 h) {
    union { unsigned u; float f; } c; c.u = ((unsigned)h) << 16;
    return c.f;
}

DEVI void gload_lds16(const void* g, void* l) {
    auto gp = (const __attribute__((address_space(1))) unsigned*)(unsigned long long)g;
    auto lp = (__attribute__((address_space(3))) unsigned*)(unsigned)(unsigned long long)l;
    __builtin_amdgcn_global_load_lds(gp, lp, 16, 0, 0);
}

// ---------------- prep: weight conversions [0,1024) + fused GroupNorm [1024,1536) ----------------
__global__ __launch_bounds__(256) void prep_kernel(const float* __restrict__ w1, u16* __restrict__ o1,
                                                   const float* __restrict__ w2, u16* __restrict__ o2,
                                                   const float* __restrict__ x,
                                                   const float* __restrict__ gw,
                                                   const float* __restrict__ gb,
                                                   u16* __restrict__ h) {
    const int bid = blockIdx.x;
    if (bid < 1024) {
        int i = bid * 256 + threadIdx.x;   // of 262144 float4 slots
        const float* src; u16* dst; int j;
        if (i < 196608) { src = w1; dst = o1; j = i; }
        else            { src = w2; dst = o2; j = i - 196608; }
        float4 v = *(const float4*)&src[j * 4];
        u16x4 p; p[0] = f2bf(v.x); p[1] = f2bf(v.y); p[2] = f2bf(v.z); p[3] = f2bf(v.w);
        *(u16x4*)&dst[j * 4] = p;
        return;
    }
    // ---- GroupNorm: single global read, stats + apply in regs ----
    const int bg = bid - 1024;           // b*32+g
    const int b = bg >> 5, g = bg & 31;
    const float* xg = x + (long long)bg * 16384;
    const int n0 = threadIdx.x * 4;

    float4 xv[16];
    float s = 0.f, s2 = 0.f;
    #pragma unroll
    for (int cc = 0; cc < 16; cc++) {
        xv[cc] = *(const float4*)&xg[cc * 1024 + n0];
        s  += xv[cc].x + xv[cc].y + xv[cc].z + xv[cc].w;
        s2 += xv[cc].x*xv[cc].x + xv[cc].y*xv[cc].y + xv[cc].z*xv[cc].z + xv[cc].w*xv[cc].w;
    }
    #pragma unroll
    for (int m = 1; m < 64; m <<= 1) { s += __shfl_xor(s, m, 64); s2 += __shfl_xor(s2, m, 64); }
    __shared__ float rs[4], rq[4];
    if ((threadIdx.x & 63) == 0) { rs[threadIdx.x >> 6] = s; rq[threadIdx.x >> 6] = s2; }
    __syncthreads();
    float mean = (rs[0] + rs[1] + rs[2] + rs[3]) * (1.f / 16384.f);
    float var  = (rq[0] + rq[1] + rq[2] + rq[3]) * (1.f / 16384.f) - mean * mean;
    float rstd = rsqrtf(var + 1e-5f);

    u16x8 o[4][2];
    #pragma unroll
    for (int cc = 0; cc < 16; cc++) {
        int c = g * 16 + cc;
        float sc = gw[c] * rstd;
        float sh = gb[c] - mean * sc;
        o[0][cc >> 3][cc & 7] = f2bf(xv[cc].x * sc + sh);
        o[1][cc >> 3][cc & 7] = f2bf(xv[cc].y * sc + sh);
        o[2][cc >> 3][cc & 7] = f2bf(xv[cc].z * sc + sh);
        o[3][cc >> 3][cc & 7] = f2bf(xv[cc].w * sc + sh);
    }
    u16* hb = h + ((long long)b * 1024 + n0) * 512 + g * 16;
    #pragma unroll
    for (int k = 0; k < 4; k++) {
        *(u16x8*)&hb[(long long)k * 512]     = o[k][0];
        *(u16x8*)&hb[(long long)k * 512 + 8] = o[k][1];
    }
}

// ---------------- TN GEMM body, 128x128 tile, BK=64 (smem passed in: 32 KB) ----------------
// MODE 1: bf16 out, scaled ([m][n]); STATS: store E = exp(acc*scale) + per-row partial
//         sum(E) per key-block
// MODE 2: bf16 transposed out C0[n][m] + bias[m]
// MODE 3: fp32 out = acc*invl[n] + bias[m] + res. aux = psum; invl computed in-kernel.
template <int MODE, bool STATS>
DEVI void gemm_body(u16* smem, int bx, int by, int bz,
                    const u16* __restrict__ A, const u16* __restrict__ Bt,
                    void* __restrict__ C0,
                    const float* __restrict__ bias, const float* __restrict__ res,
                    float* __restrict__ aux,
                    float scale, int lda, int ldb, int ldc,
                    long long sA, long long sB, long long sC, long long sR, int K) {
    const int t    = threadIdx.x;
    const int lane = t & 63;
    const int wave = t >> 6;
    const int m0   = by * 128;
    const int n0   = bx * 128;
    A  += (long long)bz * sA;
    Bt += (long long)bz * sB;

    u16* As = smem;
    u16* Bs = smem + 8192;

    const int wm = wave >> 1, wn = wave & 1;
    const int quad = lane >> 4, lrow = lane & 15;

    floatx4 acc[4][4];
    #pragma unroll
    for (int i = 0; i < 4; i++)
        #pragma unroll
        for (int j = 0; j < 4; j++)
            #pragma unroll
            for (int r = 0; r < 4; r++) acc[i][j][r] = 0.f;

    const int rowA = t >> 2;
    const int kch  = (t & 3) * 8;
    const u16* Ag = A  + (long long)(m0 + rowA) * lda + kch;
    const u16* Bg = Bt + (long long)(n0 + rowA) * ldb + kch;
    u16* Al = &As[t * 8];
    u16* Bl = &Bs[t * 8];
    const long long a64 = (long long)64 * lda;
    const long long b64 = (long long)64 * ldb;

    for (int k0 = 0; k0 < K; k0 += 64) {
        gload_lds16(Ag + k0,            Al);
        gload_lds16(Ag + k0 + a64,      Al + 2048);
        gload_lds16(Ag + k0 + 32,       Al + 4096);
        gload_lds16(Ag + k0 + 32 + a64, Al + 6144);
        gload_lds16(Bg + k0,            Bl);
        gload_lds16(Bg + k0 + b64,      Bl + 2048);
        gload_lds16(Bg + k0 + 32,       Bl + 4096);
        gload_lds16(Bg + k0 + 32 + b64, Bl + 6144);
        __syncthreads();
        #pragma unroll
        for (int kk = 0; kk < 2; kk++) {
            short8 af[4], bfr[4];
            #pragma unroll
            for (int i = 0; i < 4; i++)
                af[i] = *(const short8*)&As[kk*4096 + (wm*64 + i*16 + lrow)*32 + quad*8];
            #pragma unroll
            for (int j = 0; j < 4; j++)
                bfr[j] = *(const short8*)&Bs[kk*4096 + (wn*64 + j*16 + lrow)*32 + quad*8];
            #pragma unroll
            for (int i = 0; i < 4; i++)
                #pragma unroll
                for (int j = 0; j < 4; j++)
                    acc[i][j] = __builtin_amdgcn_mfma_f32_16x16x32_bf16(af[i], bfr[j], acc[i][j], 0, 0, 0);
        }
        __syncthreads();
    }
    // smem free from here

    const int ST = 136;  // u16 row stride (272 B = 17*16)

    if constexpr (MODE == 1) {
        #pragma unroll
        for (int p = 0; p < 4; p++) {
            if (p) __syncthreads();
            if (wm == (p >> 1)) {
                #pragma unroll
                for (int ii = 0; ii < 2; ii++) {
                    const int i = (p & 1) * 2 + ii;
                    const int row = ii * 16 + quad * 4;
                    #pragma unroll
                    for (int j = 0; j < 4; j++) {
                        const int cB = wn * 64 + j * 16 + lrow;
                        #pragma unroll
                        for (int r = 0; r < 4; r++) {
                            float v = acc[i][j][r] * scale;
                            if (STATS) v = __expf(v);          // store E = exp(S*scale)
                            smem[(row + r) * ST + cB] = f2bf(v);
                        }
                    }
                }
            }
            __syncthreads();
            const int rr = t >> 3, cc = (t & 7) * 16;
            u16x8 a0 = *(u16x8*)&smem[rr * ST + cc];
            u16x8 a1 = *(u16x8*)&smem[rr * ST + cc + 8];
            u16* Cp = (u16*)C0 + (long long)bz * sC + (long long)(m0 + p * 32 + rr) * ldc + n0 + cc;
            *(u16x8*)Cp = a0;
            *(u16x8*)(Cp + 8) = a1;
            if (STATS) {
                // partial sum of E over this block's 128 key-cols, per query row
                // (sums the SAME bf16 values used as the softmax numerator)
                float ls = 0.f;
                #pragma unroll
                for (int e = 0; e < 8; e++)
                    ls += bf2f(a0[e]) + bf2f(a1[e]);
                #pragma unroll
                for (int m2 = 1; m2 < 8; m2 <<= 1) ls += __shfl_xor(ls, m2, 8);
                if ((t & 7) == 0)
                    aux[((long long)(bz * 8 + bx)) * 1024 + m0 + p * 32 + rr] = ls;
            }
        }
    } else if constexpr (MODE == 2) {
        #pragma unroll
        for (int p = 0; p < 4; p++) {
            if (p) __syncthreads();
            if (wn == (p >> 1)) {
                #pragma unroll
                for (int jj = 0; jj < 2; jj++) {
                    const int j = (p & 1) * 2 + jj;
                    const int row = jj * 16 + lrow;
                    #pragma unroll
                    for (int i = 0; i < 4; i++) {
                        const int mmL = wm * 64 + i * 16 + quad * 4;
                        u16x4 pk;
                        #pragma unroll
                        for (int r = 0; r < 4; r++)
                            pk[r] = f2bf(acc[i][j][r] + bias[m0 + mmL + r]);
                        *(u16x4*)&smem[row * ST + mmL] = pk;
                    }
                }
            }
            __syncthreads();
            const int rr = t >> 3, cc = (t & 7) * 16;
            u16x8 a0 = *(u16x8*)&smem[rr * ST + cc];
            u16x8 a1 = *(u16x8*)&smem[rr * ST + cc + 8];
            u16* Cp = (u16*)C0 + (long long)(n0 + p * 32 + rr) * ldc + m0 + cc;
            *(u16x8*)Cp = a0;
            *(u16x8*)(Cp + 8) = a1;
        }
    } else {
        // MODE 3: fp32 out = acc*invl[col] + bias[row] + res ; invl from psum in-kernel
        __shared__ float sinv[128];
        if (t < 128) {
            const float* pz = aux + ((long long)bz * 8) * 1024 + n0 + t;
            float l = 0.f;
            #pragma unroll
            for (int kb = 0; kb < 8; kb++) l += pz[(long long)kb * 1024];
            sinv[t] = 1.f / l;
        }
        float* smf = (float*)smem;
        const int SF = 132;
        float* C = (float*)C0 + (long long)bz * sC;
        const float* rz = res + (long long)bz * sR;
        #pragma unroll
        for (int p = 0; p < 8; p++) {
            if (p) __syncthreads();
            if (wm == (p >> 2)) {
                const int i = p & 3;
                #pragma unroll
                for (int j = 0; j < 4; j++) {
                    const int cB = wn * 64 + j * 16 + lrow;
                    #pragma unroll
                    for (int r = 0; r < 4; r++)
                        smf[(quad * 4 + r) * SF + cB] = acc[i][j][r];
                }
            }
            __syncthreads();   // orders sinv writes (p=0) and smf writes before reads
            const int rr = t >> 4, cc = (t & 15) * 8;
            const float bsv = bias[m0 + p * 16 + rr];
            float4 il0 = *(const float4*)&sinv[cc];
            float4 il1 = *(const float4*)&sinv[cc + 4];
            const long long gro = (long long)(m0 + p * 16 + rr) * ldc + n0 + cc;
            float4 rv0 = *(const float4*)&rz[gro];
            float4 rv1 = *(const float4*)&rz[gro + 4];
            float4 ov0, ov1;
            ov0.x = smf[rr*SF + cc + 0] * il0.x + bsv + rv0.x;
            ov0.y = smf[rr*SF + cc + 1] * il0.y + bsv + rv0.y;
            ov0.z = smf[rr*SF + cc + 2] * il0.z + bsv + rv0.z;
            ov0.w = smf[rr*SF + cc + 3] * il0.w + bsv + rv0.w;
            ov1.x = smf[rr*SF + cc + 4] * il1.x + bsv + rv1.x;
            ov1.y = smf[rr*SF + cc + 5] * il1.y + bsv + rv1.y;
            ov1.z = smf[rr*SF + cc + 6] * il1.z + bsv + rv1.z;
            ov1.w = smf[rr*SF + cc + 7] * il1.w + bsv + rv1.w;
            *(float4*)&C[gro]     = ov0;
            *(float4*)&C[gro + 4] = ov1;
        }
    }
}

// ---------------- standalone GEMM wrapper ----------------
// NX>0: 1D launch, decoded so batch z runs on XCD z&7.
template <int MODE, int NX, int NY, bool STATS, int MINW = 3>
__global__ __launch_bounds__(256, MINW)
void gemm_bt_kernel(const u16* __restrict__ A, const u16* __restrict__ Bt,
                    void* __restrict__ C0,
                    const float* __restrict__ bias, const float* __restrict__ res,
                    float* __restrict__ aux,
                    float scale, int lda, int ldb, int ldc,
                    long long sA, long long sB, long long sC, long long sR, int K) {
    int bx, by, bz;
    if (NX > 0) {
        const int lid  = blockIdx.x;
        const int xcd  = lid & 7;
        const int slot = lid >> 3;
        const int per  = NX * NY;
        const int j    = slot / per;
        const int w    = slot - j * per;
        bz = xcd + 8 * j;
        bx = w % NX;
        by = w / NX;
    } else {
        bx = blockIdx.x; by = blockIdx.y; bz = blockIdx.z;
    }
    __shared__ __align__(16) u16 smem[16384];   // 32 KB: A[2][128][32] | B[2][128][32]
    gemm_body<MODE, STATS>(smem, bx, by, bz, A, Bt, C0, bias, res, aux,
                           scale, lda, ldb, ldc, sA, sB, sC, sR, K);
}

// ---------------- merged V' + E dispatch ----------------
// blocks [0,512):    V' = Wo @ V^T  (M=512, Nn=16384, K=512), plain decode
// blocks [512,1536): E = exp(q k^T * scale) per batch, XCD-affine decode + sum(E) stats
__global__ __launch_bounds__(256, 3)
void ve_kernel(const u16* __restrict__ wo, const u16* __restrict__ qkv_t,
               u16* __restrict__ vprm, u16* __restrict__ E, float* __restrict__ psum,
               float scale) {
    __shared__ __align__(16) u16 smem[16384];
    const int bid = blockIdx.x;
    if (bid < 512) {
        const int bx = bid & 127, by = bid >> 7;
        gemm_body<1, false>(smem, bx, by, 0, wo, qkv_t + 1024, vprm,
                            nullptr, nullptr, nullptr, 1.0f,
                            512, 1536, 16384, 0, 0, 0, 0, 512);
    } else {
        const int lid  = bid - 512;           // 512 % 8 == 0 -> XCD phase preserved
        const int xcd  = lid & 7;
        const int slot = lid >> 3;
        const int j    = slot >> 6;           // per = 8*8 = 64
        const int w    = slot & 63;
        const int bz = xcd + 8 * j;
        const int bx = w & 7, by = w >> 3;
        gemm_body<1, true>(smem, bx, by, bz, qkv_t, qkv_t + 512, E,
                           nullptr, nullptr, psum, scale,
                           1536, 1536, 1024,
                           (long long)1024*1536, (long long)1024*1536,
                           (long long)1024*1024, 0, 512);
    }
}

extern "C" void kernel_launch(void* const* d_in, const int* in_sizes, int n_in,
                              void* d_out, int out_size, void* d_ws, size_t ws_size,
                              hipStream_t stream) {
    (void)in_sizes; (void)n_in; (void)out_size; (void)ws_size;
    const float* x     = (const float*)d_in[0];
    const float* gn_w  = (const float*)d_in[1];
    const float* gn_b  = (const float*)d_in[2];
    const float* qkv_w = (const float*)d_in[3];
    const float* qkv_b = (const float*)d_in[4];
    const float* out_w = (const float*)d_in[5];
    const float* out_b = (const float*)d_in[6];
    float* out = (float*)d_out;

    char* ws = (char*)d_ws;
    u16*  h_t   = (u16*)ws;  ws += (size_t)16*1024*512*2;    // 16 MB h[b][n][c]
    u16*  qkv_t = (u16*)ws;  ws += (size_t)16*1024*1536*2;   // 48 MB qkv[b*n][1536]
    u16*  vprm  = (u16*)ws;  ws += (size_t)512*16384*2;      // 16 MB V' = Wo V^T : [c_out][b*1024+n]
    u16*  E     = (u16*)ws;  ws += (size_t)16*1024*1024*2;   // 32 MB E[b][n][m] = exp(S*scale), bf16
    u16*  wq    = (u16*)ws;  ws += (size_t)1536*512*2;
    u16*  wo    = (u16*)ws;  ws += (size_t)512*512*2;
    float* psum = (float*)ws; ws += (size_t)16*8*1024*4;     // partial sum(E) per key-block

    // weight conversion + GroupNorm in one launch
    prep_kernel<<<1536, 256, 0, stream>>>(qkv_w, wq, out_w, wo, x, gn_w, gn_b, h_t);

    // QKV: M=1536, Nn=16384, K=512 ; all transposed -> qkv_t[bn][1536] + bias
    // 1536 blocks = exactly 2 full rounds at 3 blocks/CU.
    gemm_bt_kernel<2, 0, 0, false, 3><<<dim3(128, 12, 1), 256, 0, stream>>>(
        wq, h_t, qkv_t, qkv_b, nullptr, nullptr, 1.0f,
        512, 512, 1536, 0, 0, 0, 0, 512);

    // V' (512 blocks) + E (1024 blocks) merged: independent post-QKV GEMMs, uniform
    // per-block work, 1536 = exactly 2 full rounds at 3 blocks/CU.
    ve_kernel<<<1536, 256, 0, stream>>>(wo, qkv_t, vprm, E, psum, 0.044194173824159216f);

    // out = vprm ⊗ E * invl + out_b + x : M=512, Nn=1024(n), K=1024(m) ; XCD-affine,
    // plain DMA B, invl computed in-kernel from psum
    gemm_bt_kernel<3, 8, 4, false, 3><<<512, 256, 0, stream>>>(
        vprm, E, out, out_b, x, psum, 1.0f,
        16384, 1024, 1024,
        1024, (long long)1024*1024, (long long)512*1024, (long long)512*1024, 1024);
}